// Round 10
// baseline (736.898 us; speedup 1.0000x reference)
//
#include <hip/hip_runtime.h>

using f32x4  = __attribute__((ext_vector_type(4))) float;
using short8 = __attribute__((ext_vector_type(8))) short;

__device__ inline short f2bf(float x) {
    union { float f; unsigned u; } v; v.f = x;
    unsigned r = v.u + 0x7fffu + ((v.u >> 16) & 1u);   // RNE
    return (short)(r >> 16);
}

__device__ inline short8 pack8(float4 a, float4 b) {
    short8 r;
    r[0] = f2bf(a.x); r[1] = f2bf(a.y); r[2] = f2bf(a.z); r[3] = f2bf(a.w);
    r[4] = f2bf(b.x); r[5] = f2bf(b.y); r[6] = f2bf(b.z); r[7] = f2bf(b.w);
    return r;
}

// HW packed-bf16 atomic add (proven rounds 3-7: WRITE_SIZE ~32 MB).
// The intrinsic unsafeAtomicAdd(__hip_bfloat162*) falls back to a CAS loop
// (round 9: WRITE 468 MB, FETCH +450 MB, edge +150 us) — keep the raw asm.
__device__ inline void atomic_pk_add_bf16(short* addr, unsigned pk) {
    asm volatile("global_atomic_pk_add_bf16 %0, %1, off"
                 :: "v"(addr), "v"(pk) : "memory");
}

// fast tanh: tanh(x) = 1 - 2/(e^{2x}+1); rcp/exp HW ops, plenty for bf16 tol
__device__ inline float fast_tanh(float x) {
    const float ex = __expf(2.0f * x);
    return 1.0f - 2.0f * __builtin_amdgcn_rcpf(ex + 1.0f);
}

// ---------------------------------------------------------------------------
// Weight prep: f32 -> bf16 transposed. Layer-1 K permuted:
// k 0..63 = h_src rows; 64..127 = h_dst rows; 128..143 = ea (orig 129..144);
// 144 = dist2 (orig 128); 145..159 = zero. WnT[64][128] for node MLP.
// ---------------------------------------------------------------------------
__global__ __launch_bounds__(256) void convert_weights(
    const float* __restrict__ We1, const float* __restrict__ We2,
    const float* __restrict__ Wc1, const float* __restrict__ Wn,
    short* __restrict__ W1T, short* __restrict__ W2T,
    short* __restrict__ Wc1T, short* __restrict__ WnT)
{
    const int i = blockIdx.x * 256 + threadIdx.x;
    if (i < 64 * 160) {
        const int n = i / 160, k = i % 160;
        float v = 0.0f;
        if (k < 128)       v = We1[k * 64 + n];
        else if (k < 144)  v = We1[(129 + k - 128) * 64 + n];
        else if (k == 144) v = We1[128 * 64 + n];
        W1T[i] = f2bf(v);
    }
    if (i < 64 * 128) {
        const int n = i / 128, k = i % 128;
        WnT[i] = f2bf(Wn[k * 64 + n]);
    }
    if (i < 64 * 64) {
        const int n = i / 64, k = i % 64;
        W2T[i]  = f2bf(We2[k * 64 + n]);
        Wc1T[i] = f2bf(Wc1[k * 64 + n]);
    }
}

__global__ __launch_bounds__(256) void convert_h(
    const float* __restrict__ h, short* __restrict__ hb, int n8)
{
    const int i = blockIdx.x * 256 + threadIdx.x;
    if (i < n8) {
        const float4* h4 = reinterpret_cast<const float4*>(h);
        reinterpret_cast<short8*>(hb)[i] = pack8(h4[2 * i], h4[2 * i + 1]);
    }
}

// ---------------------------------------------------------------------------
// CSR build: count -> 3-kernel coalesced scan -> fill(+gather src/dst/ea).
// ---------------------------------------------------------------------------
__global__ __launch_bounds__(256) void count_kernel(
    const int* __restrict__ ei, int* __restrict__ cnt, int E)
{
    const int e = blockIdx.x * 256 + threadIdx.x;
    if (e < E) atomicAdd(&cnt[ei[E + e]], 1);
}

__global__ __launch_bounds__(1024) void scan_partial(
    const int* __restrict__ cnt, int* __restrict__ bsum, int N)
{
    __shared__ int ws[16];
    const int i = blockIdx.x * 1024 + threadIdx.x;
    int v = (i < N) ? cnt[i] : 0;
    #pragma unroll
    for (int off = 1; off < 64; off <<= 1) v += __shfl_xor(v, off);
    const int lane = threadIdx.x & 63, wid = threadIdx.x >> 6;
    if (lane == 0) ws[wid] = v;
    __syncthreads();
    if (threadIdx.x == 0) {
        int s = 0;
        #pragma unroll
        for (int w = 0; w < 16; ++w) s += ws[w];
        bsum[blockIdx.x] = s;
    }
}

__global__ __launch_bounds__(1024) void scan_bsum(
    const int* __restrict__ bsum, int* __restrict__ boff, int NB)
{
    __shared__ int arr[1024];
    const int t = threadIdx.x;
    const int v = (t < NB) ? bsum[t] : 0;
    arr[t] = v;
    __syncthreads();
    for (int off = 1; off < 1024; off <<= 1) {
        const int u = (t >= off) ? arr[t - off] : 0;
        __syncthreads();
        arr[t] += u;
        __syncthreads();
    }
    if (t < NB) boff[t] = arr[t] - v;   // exclusive prefix of block sums
}

__global__ __launch_bounds__(1024) void scan_final(
    const int* __restrict__ cnt, const int* __restrict__ boff,
    int* __restrict__ start, int N, int E)
{
    __shared__ int ws[16];
    const int i = blockIdx.x * 1024 + threadIdx.x;
    const int lane = threadIdx.x & 63, wid = threadIdx.x >> 6;
    const int v = (i < N) ? cnt[i] : 0;
    int inc = v;
    #pragma unroll
    for (int off = 1; off < 64; off <<= 1) {
        const int u = __shfl_up(inc, off);
        if (lane >= off) inc += u;
    }
    if (lane == 63) ws[wid] = inc;
    __syncthreads();
    int wpre = 0;
    #pragma unroll
    for (int w = 0; w < 16; ++w) wpre += (w < wid) ? ws[w] : 0;
    if (i < N) start[i] = boff[blockIdx.x] + wpre + inc - v;
    if (i == 0) start[N] = E;
}

// fill + gather: place edge e at its dst-sorted slot, and materialize
// slot-ordered srcS/dstS/eaS(bf16) so the edge kernel reads them coalesced.
__global__ __launch_bounds__(256) void fill_gather(
    const int* __restrict__ ei, const float* __restrict__ ea,
    const int* __restrict__ start, int* __restrict__ cursor,
    int* __restrict__ srcS, int* __restrict__ dstS,
    short* __restrict__ eaS, int E)
{
    const int e = blockIdx.x * 256 + threadIdx.x;
    if (e < E) {
        const int s = ei[e];
        const int d = ei[E + e];
        const int slot = start[d] + atomicAdd(&cursor[d], 1);
        srcS[slot] = s;
        dstS[slot] = d;
        const float4* eap = reinterpret_cast<const float4*>(ea + (size_t)e * 16);
        short8* o = reinterpret_cast<short8*>(eaS + (size_t)slot * 16);
        o[0] = pack8(eap[0], eap[1]);
        o[1] = pack8(eap[2], eap[3]);
    }
}

// ---------------------------------------------------------------------------
// Edge pipeline, software-pipelined: each wave owns NT=4 contiguous 16-slot
// tiles (64 edges). 2-stage prefetch: idx 2 tiles ahead, src-side data
// (hb rows, pos, eaS) 1 tile ahead. dst-side loads at compute time (sorted
// runs -> L1/L2-hot). All future-tile loads issue BEFORE current tile's
// atomics. Segmented run reduction -> one pk-bf16 atomic batch per run.
// mfma_f32_16x16x32_bf16; D: col=lane&15, row=(lane>>4)*4+reg  [m89].
// ---------------------------------------------------------------------------
struct Idx { int s, d; };
struct Dat { short8 a0, a1, ae; float px, py, pz; };

__device__ inline Idx load_idx(const int* __restrict__ srcS,
                               const int* __restrict__ dstS, int slotc)
{
    Idx I; I.s = srcS[slotc]; I.d = dstS[slotc]; return I;
}

__device__ inline Dat load_dat(const short* __restrict__ hb,
                               const float* __restrict__ pos,
                               const short* __restrict__ eaS,
                               const Idx I, int slotc, int kg)
{
    Dat D;
    const short8* hs = reinterpret_cast<const short8*>(hb + (size_t)I.s * 64);
    D.a0 = hs[kg];
    D.a1 = hs[4 + kg];
    short8 ae = {0, 0, 0, 0, 0, 0, 0, 0};
    if (kg < 2) ae = *reinterpret_cast<const short8*>(eaS + (size_t)slotc * 16 + kg * 8);
    D.ae = ae;
    D.px = pos[3 * I.s + 0];
    D.py = pos[3 * I.s + 1];
    D.pz = pos[3 * I.s + 2];
    return D;
}

__global__ __launch_bounds__(256, 6) void egnn_edge_sorted(
    const short* __restrict__ hb, const float* __restrict__ pos,
    const int* __restrict__ srcS, const int* __restrict__ dstS,
    const short* __restrict__ eaS,
    const short* __restrict__ W1T, const short* __restrict__ W2T,
    const short* __restrict__ Wc1T,
    const float* __restrict__ be1, const float* __restrict__ be2,
    const float* __restrict__ bc1, const float* __restrict__ bc2,
    const float* __restrict__ Wc2,
    short* __restrict__ aggb, float* __restrict__ dpos, int E)
{
    constexpr int NT = 4;
    __shared__ short M[4][16][72];      // 9216 B, wave-private ping-pong

    const int tid  = threadIdx.x;
    const int lane = tid & 63;
    const int wave = tid >> 6;
    const int r16  = lane & 15;
    const int kg   = lane >> 4;

    const int sbase = (blockIdx.x * 4 + wave) * (16 * NT);

    // ---- pipeline prologue ----
    Idx ia = load_idx(srcS, dstS, min(sbase + r16, E - 1));
    Dat da = load_dat(hb, pos, eaS, ia, min(sbase + r16, E - 1), kg);
    Idx ib = load_idx(srcS, dstS, min(sbase + 16 + r16, E - 1));

    #pragma unroll
    for (int t = 0; t < NT; ++t) {
        // ---- prefetch (all loads BEFORE this tile's atomics) ----
        Dat dn;
        Idx in2 = ib;
        if (t + 1 < NT)
            dn = load_dat(hb, pos, eaS, ib, min(sbase + (t + 1) * 16 + r16, E - 1), kg);
        if (t + 2 < NT)
            in2 = load_idx(srcS, dstS, min(sbase + (t + 2) * 16 + r16, E - 1));

        // ================= compute tile t =================
        const int slot = sbase + t * 16 + r16;
        const int dkey = (slot < E) ? ia.d : -1;

        // dst-side loads (dst-sorted -> cache-hot)
        const short8* hd = reinterpret_cast<const short8*>(hb + (size_t)ia.d * 64);
        const short8 a2 = hd[kg];
        const short8 a3 = hd[4 + kg];
        float dx = pos[3 * ia.d + 0] - da.px;
        float dy = pos[3 * ia.d + 1] - da.py;
        float dz = pos[3 * ia.d + 2] - da.pz;
        const float d2 = fminf(dx * dx + dy * dy + dz * dz, 1000.0f);
        const float rinv = 1.0f / sqrtf(d2 + 1e-8f);
        dx *= rinv; dy *= rinv; dz *= rinv;

        short8 a4 = da.ae;
        if (kg == 2) a4[0] = f2bf(d2);

        // ---- GEMM1: [16,160] @ [160,64] ----
        f32x4 acc1[4];
        #pragma unroll
        for (int nt = 0; nt < 4; ++nt) {
            const float b = be1[r16 + nt * 16];
            acc1[nt] = {b, b, b, b};
        }
        #pragma unroll
        for (int nt = 0; nt < 4; ++nt) {
            const short* wr = W1T + (r16 + nt * 16) * 160 + kg * 8;
            acc1[nt] = __builtin_amdgcn_mfma_f32_16x16x32_bf16(
                da.a0, *reinterpret_cast<const short8*>(wr), acc1[nt], 0, 0, 0);
            acc1[nt] = __builtin_amdgcn_mfma_f32_16x16x32_bf16(
                da.a1, *reinterpret_cast<const short8*>(wr + 32), acc1[nt], 0, 0, 0);
            acc1[nt] = __builtin_amdgcn_mfma_f32_16x16x32_bf16(
                a2, *reinterpret_cast<const short8*>(wr + 64), acc1[nt], 0, 0, 0);
            acc1[nt] = __builtin_amdgcn_mfma_f32_16x16x32_bf16(
                a3, *reinterpret_cast<const short8*>(wr + 96), acc1[nt], 0, 0, 0);
            acc1[nt] = __builtin_amdgcn_mfma_f32_16x16x32_bf16(
                a4, *reinterpret_cast<const short8*>(wr + 128), acc1[nt], 0, 0, 0);
        }
        #pragma unroll
        for (int nt = 0; nt < 4; ++nt)
            #pragma unroll
            for (int rg = 0; rg < 4; ++rg)
                M[wave][kg * 4 + rg][r16 + nt * 16] = f2bf(fmaxf(acc1[nt][rg], 0.0f));

        // ---- GEMM2 (f32 acc kept for run-aggregation) ----
        const short8 a5 = *reinterpret_cast<const short8*>(&M[wave][r16][kg * 8]);
        const short8 a6 = *reinterpret_cast<const short8*>(&M[wave][r16][32 + kg * 8]);
        f32x4 acc2[4];
        #pragma unroll
        for (int nt = 0; nt < 4; ++nt) {
            const float b = be2[r16 + nt * 16];
            acc2[nt] = {b, b, b, b};
        }
        #pragma unroll
        for (int nt = 0; nt < 4; ++nt) {
            const short* wr = W2T + (r16 + nt * 16) * 64 + kg * 8;
            acc2[nt] = __builtin_amdgcn_mfma_f32_16x16x32_bf16(
                a5, *reinterpret_cast<const short8*>(wr), acc2[nt], 0, 0, 0);
            acc2[nt] = __builtin_amdgcn_mfma_f32_16x16x32_bf16(
                a6, *reinterpret_cast<const short8*>(wr + 32), acc2[nt], 0, 0, 0);
        }
        #pragma unroll
        for (int nt = 0; nt < 4; ++nt)
            #pragma unroll
            for (int rg = 0; rg < 4; ++rg) {
                const float v = fmaxf(acc2[nt][rg], 0.0f);
                acc2[nt][rg] = v;
                M[wave][kg * 4 + rg][r16 + nt * 16] = f2bf(v);
            }

        // ---- GEMM3: coord MLP layer 1 ----
        const short8 a7 = *reinterpret_cast<const short8*>(&M[wave][r16][kg * 8]);
        const short8 a8 = *reinterpret_cast<const short8*>(&M[wave][r16][32 + kg * 8]);
        f32x4 acc3[4];
        #pragma unroll
        for (int nt = 0; nt < 4; ++nt) {
            const float b = bc1[r16 + nt * 16];
            acc3[nt] = {b, b, b, b};
        }
        #pragma unroll
        for (int nt = 0; nt < 4; ++nt) {
            const short* wr = Wc1T + (r16 + nt * 16) * 64 + kg * 8;
            acc3[nt] = __builtin_amdgcn_mfma_f32_16x16x32_bf16(
                a7, *reinterpret_cast<const short8*>(wr), acc3[nt], 0, 0, 0);
            acc3[nt] = __builtin_amdgcn_mfma_f32_16x16x32_bf16(
                a8, *reinterpret_cast<const short8*>(wr + 32), acc3[nt], 0, 0, 0);
        }

        // ---- coef rows: cf[rg] for rows kg*4+rg ----
        float cf[4] = {0.0f, 0.0f, 0.0f, 0.0f};
        #pragma unroll
        for (int nt = 0; nt < 4; ++nt) {
            const float wv = Wc2[r16 + nt * 16];
            #pragma unroll
            for (int rg = 0; rg < 4; ++rg)
                cf[rg] += fmaxf(acc3[nt][rg], 0.0f) * wv;
        }
        #pragma unroll
        for (int off = 1; off < 16; off <<= 1)
            #pragma unroll
            for (int rg = 0; rg < 4; ++rg)
                cf[rg] += __shfl_xor(cf[rg], off);
        const float bc2v = bc2[0];
        #pragma unroll
        for (int rg = 0; rg < 4; ++rg)
            cf[rg] = fast_tanh(cf[rg] + bc2v) * 0.1f;

        // cfown = coef for this lane's OWN row r16
        const int srcl = ((r16 >> 2) << 4) + r16;
        const float c0 = __shfl(cf[0], srcl);
        const float c1 = __shfl(cf[1], srcl);
        const float c2 = __shfl(cf[2], srcl);
        const float c3 = __shfl(cf[3], srcl);
        const int rsel = r16 & 3;
        const float cfown = (rsel == 0) ? c0 : (rsel == 1) ? c1 : (rsel == 2) ? c2 : c3;

        // ---- segmented run reduction, one atomic batch per run ----
        int rstart = 0;
        while (rstart < 16) {
            const int dcur = __shfl(dkey, rstart);
            const bool inrun = (dkey == dcur) && (r16 >= rstart);
            const unsigned long long bm = __ballot(inrun);
            const int len = __popc((unsigned)bm & 0xFFFFu);
            const int rend = rstart + len;

            float s0 = 0.0f, s1 = 0.0f, s2 = 0.0f, s3 = 0.0f;
            #pragma unroll
            for (int rg = 0; rg < 4; ++rg) {
                const int row = (kg << 2) + rg;
                if (row >= rstart && row < rend) {
                    s0 += acc2[0][rg]; s1 += acc2[1][rg];
                    s2 += acc2[2][rg]; s3 += acc2[3][rg];
                }
            }
            s0 += __shfl_xor(s0, 16); s0 += __shfl_xor(s0, 32);
            s1 += __shfl_xor(s1, 16); s1 += __shfl_xor(s1, 32);
            s2 += __shfl_xor(s2, 16); s2 += __shfl_xor(s2, 32);
            s3 += __shfl_xor(s3, 16); s3 += __shfl_xor(s3, 32);

            float tx = inrun ? cfown * dx : 0.0f;
            float ty = inrun ? cfown * dy : 0.0f;
            float tz = inrun ? cfown * dz : 0.0f;
            #pragma unroll
            for (int off = 1; off < 16; off <<= 1) {
                tx += __shfl_xor(tx, off);
                ty += __shfl_xor(ty, off);
                tz += __shfl_xor(tz, off);
            }

            if (dcur >= 0) {
                #pragma unroll
                for (int nt = 0; nt < 4; ++nt) {
                    const float v  = (nt == 0) ? s0 : (nt == 1) ? s1 : (nt == 2) ? s2 : s3;
                    const float vp = __shfl_xor(v, 1);
                    if (kg == 0 && ((r16 & 1) == (nt >> 1))) {
                        const int col0 = (r16 & ~1) + nt * 16;
                        const unsigned blo = (unsigned short)f2bf((r16 & 1) ? vp : v);
                        const unsigned bhi = (unsigned short)f2bf((r16 & 1) ? v : vp);
                        atomic_pk_add_bf16(aggb + (size_t)dcur * 64 + col0,
                                           blo | (bhi << 16));
                    }
                }
                if (kg == 0 && r16 < 3) {
                    const float tv = (r16 == 0) ? tx : (r16 == 1) ? ty : tz;
                    unsafeAtomicAdd(&dpos[3 * dcur + r16], tv);
                }
            }
            rstart = rend;
        }
        // ================= end compute =================

        ia = ib;
        ib = in2;
        if (t + 1 < NT) da = dn;
    }
}

// ---------------------------------------------------------------------------
// Node MLP + residual + LayerNorm, MFMA version. 64 nodes/block, 4 waves.
// ---------------------------------------------------------------------------
__global__ __launch_bounds__(256) void egnn_node_mfma(
    const float* __restrict__ h, const short* __restrict__ hb,
    const short* __restrict__ aggb, const float* __restrict__ pos,
    const float* __restrict__ dpos, const short* __restrict__ WnT,
    const float* __restrict__ bn, const float* __restrict__ lng,
    const float* __restrict__ lnb,
    float* __restrict__ h_out, float* __restrict__ pos_out, int N)
{
    __shared__ short As[64][136];   // cols 0..64 = h (bf16), 64..128 = agg
    const int tid = threadIdx.x;
    const int n0  = blockIdx.x * 64;

    if (tid < 64) {
        const int n = n0 + tid;
        if (n < N) {
            #pragma unroll
            for (int c = 0; c < 3; ++c)
                pos_out[(size_t)3 * n + c] = pos[(size_t)3 * n + c] + dpos[(size_t)3 * n + c];
        }
    }

    {
        const int row = tid >> 2, part = tid & 3;
        const int n = n0 + row;
        if (n < N) {
            const short* sp = (part < 2) ? (hb + (size_t)n * 64 + (part & 1) * 32)
                                         : (aggb + (size_t)n * 64 + (part & 1) * 32);
            #pragma unroll
            for (int q = 0; q < 4; ++q)
                *reinterpret_cast<short8*>(&As[row][part * 32 + q * 8]) =
                    *reinterpret_cast<const short8*>(sp + q * 8);
        }
    }
    __syncthreads();

    const int lane = tid & 63;
    const int wave = tid >> 6;
    const int r16  = lane & 15;
    const int kg   = lane >> 4;
    const int mrow = wave * 16 + r16;

    f32x4 acc[4];
    #pragma unroll
    for (int nt = 0; nt < 4; ++nt) {
        const float b = bn[r16 + nt * 16];
        acc[nt] = {b, b, b, b};
    }
    #pragma unroll
    for (int kt = 0; kt < 4; ++kt) {
        short8 a = *reinterpret_cast<const short8*>(&As[mrow][kt * 32 + kg * 8]);
        #pragma unroll
        for (int nt = 0; nt < 4; ++nt) {
            short8 b = *reinterpret_cast<const short8*>(
                &WnT[(r16 + nt * 16) * 128 + kt * 32 + kg * 8]);
            acc[nt] = __builtin_amdgcn_mfma_f32_16x16x32_bf16(a, b, acc[nt], 0, 0, 0);
        }
    }

    float xv[4][4];
    #pragma unroll
    for (int rg = 0; rg < 4; ++rg) {
        const int n = n0 + wave * 16 + kg * 4 + rg;
        const bool ok = n < N;
        #pragma unroll
        for (int nt = 0; nt < 4; ++nt)
            xv[nt][rg] = (ok ? h[(size_t)n * 64 + r16 + nt * 16] : 0.0f)
                         + fmaxf(acc[nt][rg], 0.0f);
    }

    float g[4], bb[4];
    #pragma unroll
    for (int nt = 0; nt < 4; ++nt) { g[nt] = lng[r16 + nt * 16]; bb[nt] = lnb[r16 + nt * 16]; }

    #pragma unroll
    for (int rg = 0; rg < 4; ++rg) {
        float s = xv[0][rg] + xv[1][rg] + xv[2][rg] + xv[3][rg];
        #pragma unroll
        for (int off = 1; off < 16; off <<= 1) s += __shfl_xor(s, off);
        const float mu = s * 0.015625f;
        float q = 0.0f;
        #pragma unroll
        for (int nt = 0; nt < 4; ++nt) { const float d = xv[nt][rg] - mu; q += d * d; }
        #pragma unroll
        for (int off = 1; off < 16; off <<= 1) q += __shfl_xor(q, off);
        const float inv = rsqrtf(q * 0.015625f + 1e-5f);
        const int n = n0 + wave * 16 + kg * 4 + rg;
        if (n < N) {
            #pragma unroll
            for (int nt = 0; nt < 4; ++nt)
                h_out[(size_t)n * 64 + r16 + nt * 16] =
                    (xv[nt][rg] - mu) * inv * g[nt] + bb[nt];
        }
    }
}

extern "C" void kernel_launch(void* const* d_in, const int* in_sizes, int n_in,
                              void* d_out, int out_size, void* d_ws, size_t ws_size,
                              hipStream_t stream)
{
    const float* h   = (const float*)d_in[0];
    const float* pos = (const float*)d_in[1];
    const int*   ei  = (const int*)d_in[2];
    const float* ea  = (const float*)d_in[3];
    const float* We1 = (const float*)d_in[4];
    const float* be1 = (const float*)d_in[5];
    const float* We2 = (const float*)d_in[6];
    const float* be2 = (const float*)d_in[7];
    const float* Wc1 = (const float*)d_in[8];
    const float* bc1 = (const float*)d_in[9];
    const float* Wc2 = (const float*)d_in[10];
    const float* bc2 = (const float*)d_in[11];
    const float* Wn  = (const float*)d_in[12];
    const float* bn  = (const float*)d_in[13];
    const float* lng = (const float*)d_in[14];
    const float* lnb = (const float*)d_in[15];

    const int N = in_sizes[0] / 64;
    const int E = in_sizes[2] / 2;
    const int NB = (N + 1023) / 1024;

    // workspace layout (16B-aligned short arrays first)
    short* aggb = (short*)d_ws;                         // [N,64] bf16
    short* hbuf = aggb + (size_t)N * 64;                // [N,64] bf16
    short* eaS  = hbuf + (size_t)N * 64;                // [E,16] bf16 (sorted)
    short* W1T  = eaS + (size_t)E * 16;                 // [64,160]
    short* W2T  = W1T + 64 * 160;                       // [64,64]
    short* Wc1T = W2T + 64 * 64;                        // [64,64]
    short* WnT  = Wc1T + 64 * 64;                       // [64,128]
    float* dpos = (float*)(WnT + 64 * 128);             // [N,3]  f32
    int* cnt    = (int*)(dpos + (size_t)3 * N);         // [N]
    int* cursor = cnt + N;                              // [N]
    int* startp = cursor + N;                           // [N+1]
    int* bsum   = startp + N + 1;                       // [NB<=1024]
    int* boff   = bsum + 1024;                          // [NB]
    int* srcS   = boff + 1024;                          // [E] (sorted)
    int* dstS   = srcS + E;                             // [E] (sorted)

    (void)hipMemsetAsync(aggb, 0, (size_t)N * 128, stream);     // aggb
    (void)hipMemsetAsync(dpos, 0, (size_t)N * 20, stream);      // dpos+cnt+cursor
    convert_weights<<<40, 256, 0, stream>>>(We1, We2, Wc1, Wn, W1T, W2T, Wc1T, WnT);
    convert_h<<<(N * 64 / 8 + 255) / 256, 256, 0, stream>>>(h, hbuf, N * 64 / 8);
    count_kernel<<<(E + 255) / 256, 256, 0, stream>>>(ei, cnt, E);
    scan_partial<<<NB, 1024, 0, stream>>>(cnt, bsum, N);
    scan_bsum<<<1, 1024, 0, stream>>>(bsum, boff, NB);
    scan_final<<<NB, 1024, 0, stream>>>(cnt, boff, startp, N, E);
    fill_gather<<<(E + 255) / 256, 256, 0, stream>>>(
        ei, ea, startp, cursor, srcS, dstS, eaS, E);

    float* h_out   = (float*)d_out;
    float* pos_out = h_out + (size_t)N * 64;

    // NT=4 tiles/wave, 4 waves/block -> 256 edges per block
    egnn_edge_sorted<<<(E + 255) / 256, 256, 0, stream>>>(
        hbuf, pos, srcS, dstS, eaS, W1T, W2T, Wc1T,
        be1, be2, bc1, bc2, Wc2, aggb, dpos, E);
    egnn_node_mfma<<<(N + 63) / 64, 256, 0, stream>>>(
        h, hbuf, aggb, pos, dpos, WnT, bn, lng, lnb, h_out, pos_out, N);
}

// Round 11
// 672.562 us; speedup vs baseline: 1.0957x; 1.0957x over previous
//
#include <hip/hip_runtime.h>

using f32x4  = __attribute__((ext_vector_type(4))) float;
using short8 = __attribute__((ext_vector_type(8))) short;

__device__ inline short f2bf(float x) {
    union { float f; unsigned u; } v; v.f = x;
    unsigned r = v.u + 0x7fffu + ((v.u >> 16) & 1u);   // RNE
    return (short)(r >> 16);
}

__device__ inline short8 pack8(float4 a, float4 b) {
    short8 r;
    r[0] = f2bf(a.x); r[1] = f2bf(a.y); r[2] = f2bf(a.z); r[3] = f2bf(a.w);
    r[4] = f2bf(b.x); r[5] = f2bf(b.y); r[6] = f2bf(b.z); r[7] = f2bf(b.w);
    return r;
}

// HW packed-bf16 atomic add (proven rounds 3-7: WRITE_SIZE ~32 MB).
__device__ inline void atomic_pk_add_bf16(short* addr, unsigned pk) {
    asm volatile("global_atomic_pk_add_bf16 %0, %1, off"
                 :: "v"(addr), "v"(pk) : "memory");
}

// fast tanh: tanh(x) = 1 - 2/(e^{2x}+1)
__device__ inline float fast_tanh(float x) {
    const float ex = __expf(2.0f * x);
    return 1.0f - 2.0f * __builtin_amdgcn_rcpf(ex + 1.0f);
}

// ---------------------------------------------------------------------------
// Weight prep: f32 -> bf16 transposed. Layer-1 K permuted:
// k 0..63 = h_src rows; 64..127 = h_dst rows; 128..143 = ea (orig 129..144);
// 144 = dist2 (orig 128); 145..159 = zero. WnT[64][128] for node MLP.
// ---------------------------------------------------------------------------
__global__ __launch_bounds__(256) void convert_weights(
    const float* __restrict__ We1, const float* __restrict__ We2,
    const float* __restrict__ Wc1, const float* __restrict__ Wn,
    short* __restrict__ W1T, short* __restrict__ W2T,
    short* __restrict__ Wc1T, short* __restrict__ WnT)
{
    const int i = blockIdx.x * 256 + threadIdx.x;
    if (i < 64 * 160) {
        const int n = i / 160, k = i % 160;
        float v = 0.0f;
        if (k < 128)       v = We1[k * 64 + n];
        else if (k < 144)  v = We1[(129 + k - 128) * 64 + n];
        else if (k == 144) v = We1[128 * 64 + n];
        W1T[i] = f2bf(v);
    }
    if (i < 64 * 128) {
        const int n = i / 128, k = i % 128;
        WnT[i] = f2bf(Wn[k * 64 + n]);
    }
    if (i < 64 * 64) {
        const int n = i / 64, k = i % 64;
        W2T[i]  = f2bf(We2[k * 64 + n]);
        Wc1T[i] = f2bf(Wc1[k * 64 + n]);
    }
}

__global__ __launch_bounds__(256) void convert_h(
    const float* __restrict__ h, short* __restrict__ hb, int n8)
{
    const int i = blockIdx.x * 256 + threadIdx.x;
    if (i < n8) {
        const float4* h4 = reinterpret_cast<const float4*>(h);
        reinterpret_cast<short8*>(hb)[i] = pack8(h4[2 * i], h4[2 * i + 1]);
    }
}

// ---------------------------------------------------------------------------
// CSR build: count -> 3-kernel coalesced scan -> fill(+gather src/dst/ea).
// ---------------------------------------------------------------------------
__global__ __launch_bounds__(256) void count_kernel(
    const int* __restrict__ ei, int* __restrict__ cnt, int E)
{
    const int e = blockIdx.x * 256 + threadIdx.x;
    if (e < E) atomicAdd(&cnt[ei[E + e]], 1);
}

__global__ __launch_bounds__(1024) void scan_partial(
    const int* __restrict__ cnt, int* __restrict__ bsum, int N)
{
    __shared__ int ws[16];
    const int i = blockIdx.x * 1024 + threadIdx.x;
    int v = (i < N) ? cnt[i] : 0;
    #pragma unroll
    for (int off = 1; off < 64; off <<= 1) v += __shfl_xor(v, off);
    const int lane = threadIdx.x & 63, wid = threadIdx.x >> 6;
    if (lane == 0) ws[wid] = v;
    __syncthreads();
    if (threadIdx.x == 0) {
        int s = 0;
        #pragma unroll
        for (int w = 0; w < 16; ++w) s += ws[w];
        bsum[blockIdx.x] = s;
    }
}

__global__ __launch_bounds__(1024) void scan_bsum(
    const int* __restrict__ bsum, int* __restrict__ boff, int NB)
{
    __shared__ int arr[1024];
    const int t = threadIdx.x;
    const int v = (t < NB) ? bsum[t] : 0;
    arr[t] = v;
    __syncthreads();
    for (int off = 1; off < 1024; off <<= 1) {
        const int u = (t >= off) ? arr[t - off] : 0;
        __syncthreads();
        arr[t] += u;
        __syncthreads();
    }
    if (t < NB) boff[t] = arr[t] - v;   // exclusive prefix of block sums
}

__global__ __launch_bounds__(1024) void scan_final(
    const int* __restrict__ cnt, const int* __restrict__ boff,
    int* __restrict__ start, int N, int E)
{
    __shared__ int ws[16];
    const int i = blockIdx.x * 1024 + threadIdx.x;
    const int lane = threadIdx.x & 63, wid = threadIdx.x >> 6;
    const int v = (i < N) ? cnt[i] : 0;
    int inc = v;
    #pragma unroll
    for (int off = 1; off < 64; off <<= 1) {
        const int u = __shfl_up(inc, off);
        if (lane >= off) inc += u;
    }
    if (lane == 63) ws[wid] = inc;
    __syncthreads();
    int wpre = 0;
    #pragma unroll
    for (int w = 0; w < 16; ++w) wpre += (w < wid) ? ws[w] : 0;
    if (i < N) start[i] = boff[blockIdx.x] + wpre + inc - v;
    if (i == 0) start[N] = E;
}

// fill + gather: place edge e at its dst-sorted slot, and materialize
// slot-ordered srcS/dstS/eaS(bf16) so the edge kernel reads them coalesced.
__global__ __launch_bounds__(256) void fill_gather(
    const int* __restrict__ ei, const float* __restrict__ ea,
    const int* __restrict__ start, int* __restrict__ cursor,
    int* __restrict__ srcS, int* __restrict__ dstS,
    short* __restrict__ eaS, int E)
{
    const int e = blockIdx.x * 256 + threadIdx.x;
    if (e < E) {
        const int s = ei[e];
        const int d = ei[E + e];
        const int slot = start[d] + atomicAdd(&cursor[d], 1);
        srcS[slot] = s;
        dstS[slot] = d;
        const float4* eap = reinterpret_cast<const float4*>(ea + (size_t)e * 16);
        short8* o = reinterpret_cast<short8*>(eaS + (size_t)slot * 16);
        o[0] = pack8(eap[0], eap[1]);
        o[1] = pack8(eap[2], eap[3]);
    }
}

// ---------------------------------------------------------------------------
// Edge pipeline over dst-SORTED slots, 2-tile ILP version. Each wave owns
// TWO contiguous 16-slot tiles (A,B) in straight-line code with individually
// NAMED registers (no structs, no rotation, no conditional assignment —
// rounds 9/10's struct pipeline spilled to scratch: +450 MB FETCH/WRITE).
// All src-side loads for BOTH tiles issue in the prologue, so tile B
// computes with its data already resident. Per-tile compute identical to
// round 7 (macro). mfma_f32_16x16x32_bf16; D: col=lane&15,row=(lane>>4)*4+reg.
// ---------------------------------------------------------------------------
__global__ __launch_bounds__(256, 6) void egnn_edge_sorted(
    const short* __restrict__ hb, const float* __restrict__ pos,
    const int* __restrict__ srcS, const int* __restrict__ dstS,
    const short* __restrict__ eaS,
    const short* __restrict__ W1T, const short* __restrict__ W2T,
    const short* __restrict__ Wc1T,
    const float* __restrict__ be1, const float* __restrict__ be2,
    const float* __restrict__ bc1, const float* __restrict__ bc2,
    const float* __restrict__ Wc2,
    short* __restrict__ aggb, float* __restrict__ dpos, int E)
{
    __shared__ short M[4][16][72];      // 9216 B, wave-private ping-pong

    const int tid  = threadIdx.x;
    const int lane = tid & 63;
    const int wave = tid >> 6;
    const int r16  = lane & 15;
    const int kg   = lane >> 4;

    const int sbase = (blockIdx.x * 4 + wave) * 32;   // 2 tiles of 16 slots
    const int slotA = sbase + r16;
    const int slotB = sbase + 16 + r16;
    const int scA = min(slotA, E - 1);
    const int scB = min(slotB, E - 1);

    // ---- prologue: issue ALL src-side loads for both tiles ----
    const int srcA = srcS[scA], dstA = dstS[scA];
    const int srcB = srcS[scB], dstB = dstS[scB];

    const short8* hsA = reinterpret_cast<const short8*>(hb + (size_t)srcA * 64);
    const short8 a0A = hsA[kg];
    const short8 a1A = hsA[4 + kg];
    const short8* hsB = reinterpret_cast<const short8*>(hb + (size_t)srcB * 64);
    const short8 a0B = hsB[kg];
    const short8 a1B = hsB[4 + kg];

    short8 aeA = {0, 0, 0, 0, 0, 0, 0, 0};
    short8 aeB = {0, 0, 0, 0, 0, 0, 0, 0};
    if (kg < 2) {
        aeA = *reinterpret_cast<const short8*>(eaS + (size_t)scA * 16 + kg * 8);
        aeB = *reinterpret_cast<const short8*>(eaS + (size_t)scB * 16 + kg * 8);
    }
    const float psxA = pos[3 * srcA + 0], psyA = pos[3 * srcA + 1], pszA = pos[3 * srcA + 2];
    const float psxB = pos[3 * srcB + 0], psyB = pos[3 * srcB + 1], pszB = pos[3 * srcB + 2];

#define COMPUTE_TILE(SLOTV, DSTV, A0, A1, AE, PSX, PSY, PSZ)                  \
do {                                                                          \
    const int dkey_ = (SLOTV < E) ? DSTV : -1;                                \
    const short8* hd_ = reinterpret_cast<const short8*>(hb + (size_t)DSTV * 64); \
    const short8 a2_ = hd_[kg];                                               \
    const short8 a3_ = hd_[4 + kg];                                           \
    float dx_ = pos[3 * DSTV + 0] - PSX;                                      \
    float dy_ = pos[3 * DSTV + 1] - PSY;                                      \
    float dz_ = pos[3 * DSTV + 2] - PSZ;                                      \
    const float d2_ = fminf(dx_ * dx_ + dy_ * dy_ + dz_ * dz_, 1000.0f);      \
    const float ri_ = 1.0f / sqrtf(d2_ + 1e-8f);                              \
    dx_ *= ri_; dy_ *= ri_; dz_ *= ri_;                                       \
    short8 a4_ = AE;                                                          \
    if (kg == 2) a4_[0] = f2bf(d2_);                                          \
    f32x4 acc1_[4];                                                           \
    _Pragma("unroll")                                                         \
    for (int nt = 0; nt < 4; ++nt) {                                          \
        const float b = be1[r16 + nt * 16];                                   \
        acc1_[nt] = {b, b, b, b};                                             \
    }                                                                         \
    _Pragma("unroll")                                                         \
    for (int nt = 0; nt < 4; ++nt) {                                          \
        const short* wr = W1T + (r16 + nt * 16) * 160 + kg * 8;               \
        acc1_[nt] = __builtin_amdgcn_mfma_f32_16x16x32_bf16(                  \
            A0, *reinterpret_cast<const short8*>(wr), acc1_[nt], 0, 0, 0);    \
        acc1_[nt] = __builtin_amdgcn_mfma_f32_16x16x32_bf16(                  \
            A1, *reinterpret_cast<const short8*>(wr + 32), acc1_[nt], 0, 0, 0);\
        acc1_[nt] = __builtin_amdgcn_mfma_f32_16x16x32_bf16(                  \
            a2_, *reinterpret_cast<const short8*>(wr + 64), acc1_[nt], 0, 0, 0);\
        acc1_[nt] = __builtin_amdgcn_mfma_f32_16x16x32_bf16(                  \
            a3_, *reinterpret_cast<const short8*>(wr + 96), acc1_[nt], 0, 0, 0);\
        acc1_[nt] = __builtin_amdgcn_mfma_f32_16x16x32_bf16(                  \
            a4_, *reinterpret_cast<const short8*>(wr + 128), acc1_[nt], 0, 0, 0);\
    }                                                                         \
    _Pragma("unroll")                                                         \
    for (int nt = 0; nt < 4; ++nt)                                            \
        _Pragma("unroll")                                                     \
        for (int rg = 0; rg < 4; ++rg)                                        \
            M[wave][kg * 4 + rg][r16 + nt * 16] = f2bf(fmaxf(acc1_[nt][rg], 0.0f)); \
    const short8 a5_ = *reinterpret_cast<const short8*>(&M[wave][r16][kg * 8]);     \
    const short8 a6_ = *reinterpret_cast<const short8*>(&M[wave][r16][32 + kg * 8]);\
    f32x4 acc2_[4];                                                           \
    _Pragma("unroll")                                                         \
    for (int nt = 0; nt < 4; ++nt) {                                          \
        const float b = be2[r16 + nt * 16];                                   \
        acc2_[nt] = {b, b, b, b};                                             \
    }                                                                         \
    _Pragma("unroll")                                                         \
    for (int nt = 0; nt < 4; ++nt) {                                          \
        const short* wr = W2T + (r16 + nt * 16) * 64 + kg * 8;                \
        acc2_[nt] = __builtin_amdgcn_mfma_f32_16x16x32_bf16(                  \
            a5_, *reinterpret_cast<const short8*>(wr), acc2_[nt], 0, 0, 0);   \
        acc2_[nt] = __builtin_amdgcn_mfma_f32_16x16x32_bf16(                  \
            a6_, *reinterpret_cast<const short8*>(wr + 32), acc2_[nt], 0, 0, 0);\
    }                                                                         \
    _Pragma("unroll")                                                         \
    for (int nt = 0; nt < 4; ++nt)                                            \
        _Pragma("unroll")                                                     \
        for (int rg = 0; rg < 4; ++rg) {                                      \
            const float v = fmaxf(acc2_[nt][rg], 0.0f);                       \
            acc2_[nt][rg] = v;                                                \
            M[wave][kg * 4 + rg][r16 + nt * 16] = f2bf(v);                    \
        }                                                                     \
    const short8 a7_ = *reinterpret_cast<const short8*>(&M[wave][r16][kg * 8]);     \
    const short8 a8_ = *reinterpret_cast<const short8*>(&M[wave][r16][32 + kg * 8]);\
    f32x4 acc3_[4];                                                           \
    _Pragma("unroll")                                                         \
    for (int nt = 0; nt < 4; ++nt) {                                          \
        const float b = bc1[r16 + nt * 16];                                   \
        acc3_[nt] = {b, b, b, b};                                             \
    }                                                                         \
    _Pragma("unroll")                                                         \
    for (int nt = 0; nt < 4; ++nt) {                                          \
        const short* wr = Wc1T + (r16 + nt * 16) * 64 + kg * 8;               \
        acc3_[nt] = __builtin_amdgcn_mfma_f32_16x16x32_bf16(                  \
            a7_, *reinterpret_cast<const short8*>(wr), acc3_[nt], 0, 0, 0);   \
        acc3_[nt] = __builtin_amdgcn_mfma_f32_16x16x32_bf16(                  \
            a8_, *reinterpret_cast<const short8*>(wr + 32), acc3_[nt], 0, 0, 0);\
    }                                                                         \
    float cf_[4] = {0.0f, 0.0f, 0.0f, 0.0f};                                  \
    _Pragma("unroll")                                                         \
    for (int nt = 0; nt < 4; ++nt) {                                          \
        const float wv = Wc2[r16 + nt * 16];                                  \
        _Pragma("unroll")                                                     \
        for (int rg = 0; rg < 4; ++rg)                                        \
            cf_[rg] += fmaxf(acc3_[nt][rg], 0.0f) * wv;                       \
    }                                                                         \
    _Pragma("unroll")                                                         \
    for (int off = 1; off < 16; off <<= 1)                                    \
        _Pragma("unroll")                                                     \
        for (int rg = 0; rg < 4; ++rg)                                        \
            cf_[rg] += __shfl_xor(cf_[rg], off);                              \
    const float bc2v_ = bc2[0];                                               \
    _Pragma("unroll")                                                         \
    for (int rg = 0; rg < 4; ++rg)                                            \
        cf_[rg] = fast_tanh(cf_[rg] + bc2v_) * 0.1f;                          \
    const int srcl_ = ((r16 >> 2) << 4) + r16;                                \
    const float c0_ = __shfl(cf_[0], srcl_);                                  \
    const float c1_ = __shfl(cf_[1], srcl_);                                  \
    const float c2_ = __shfl(cf_[2], srcl_);                                  \
    const float c3_ = __shfl(cf_[3], srcl_);                                  \
    const int rsel_ = r16 & 3;                                                \
    const float cfown_ = (rsel_ == 0) ? c0_ : (rsel_ == 1) ? c1_              \
                       : (rsel_ == 2) ? c2_ : c3_;                            \
    int rstart_ = 0;                                                          \
    while (rstart_ < 16) {                                                    \
        const int dcur_ = __shfl(dkey_, rstart_);                             \
        const bool inrun_ = (dkey_ == dcur_) && (r16 >= rstart_);             \
        const unsigned long long bm_ = __ballot(inrun_);                      \
        const int len_ = __popc((unsigned)bm_ & 0xFFFFu);                     \
        const int rend_ = rstart_ + len_;                                     \
        float s0_ = 0.0f, s1_ = 0.0f, s2_ = 0.0f, s3_ = 0.0f;                 \
        _Pragma("unroll")                                                     \
        for (int rg = 0; rg < 4; ++rg) {                                      \
            const int row = (kg << 2) + rg;                                   \
            if (row >= rstart_ && row < rend_) {                              \
                s0_ += acc2_[0][rg]; s1_ += acc2_[1][rg];                     \
                s2_ += acc2_[2][rg]; s3_ += acc2_[3][rg];                     \
            }                                                                 \
        }                                                                     \
        s0_ += __shfl_xor(s0_, 16); s0_ += __shfl_xor(s0_, 32);               \
        s1_ += __shfl_xor(s1_, 16); s1_ += __shfl_xor(s1_, 32);               \
        s2_ += __shfl_xor(s2_, 16); s2_ += __shfl_xor(s2_, 32);               \
        s3_ += __shfl_xor(s3_, 16); s3_ += __shfl_xor(s3_, 32);               \
        float tx_ = inrun_ ? cfown_ * dx_ : 0.0f;                             \
        float ty_ = inrun_ ? cfown_ * dy_ : 0.0f;                             \
        float tz_ = inrun_ ? cfown_ * dz_ : 0.0f;                             \
        _Pragma("unroll")                                                     \
        for (int off = 1; off < 16; off <<= 1) {                              \
            tx_ += __shfl_xor(tx_, off);                                      \
            ty_ += __shfl_xor(ty_, off);                                      \
            tz_ += __shfl_xor(tz_, off);                                      \
        }                                                                     \
        if (dcur_ >= 0) {                                                     \
            _Pragma("unroll")                                                 \
            for (int nt = 0; nt < 4; ++nt) {                                  \
                const float v = (nt == 0) ? s0_ : (nt == 1) ? s1_             \
                              : (nt == 2) ? s2_ : s3_;                        \
                const float vp = __shfl_xor(v, 1);                            \
                if (kg == 0 && ((r16 & 1) == (nt >> 1))) {                    \
                    const int col0 = (r16 & ~1) + nt * 16;                    \
                    const unsigned blo = (unsigned short)f2bf((r16 & 1) ? vp : v); \
                    const unsigned bhi = (unsigned short)f2bf((r16 & 1) ? v : vp); \
                    atomic_pk_add_bf16(aggb + (size_t)dcur_ * 64 + col0,      \
                                       blo | (bhi << 16));                    \
                }                                                             \
            }                                                                 \
            if (kg == 0 && r16 < 3) {                                         \
                const float tv = (r16 == 0) ? tx_ : (r16 == 1) ? ty_ : tz_;   \
                unsafeAtomicAdd(&dpos[3 * dcur_ + r16], tv);                  \
            }                                                                 \
        }                                                                     \
        rstart_ = rend_;                                                      \
    }                                                                         \
} while (0)

    COMPUTE_TILE(slotA, dstA, a0A, a1A, aeA, psxA, psyA, pszA);
    COMPUTE_TILE(slotB, dstB, a0B, a1B, aeB, psxB, psyB, pszB);
#undef COMPUTE_TILE
}

// ---------------------------------------------------------------------------
// Node MLP + residual + LayerNorm, MFMA version. 64 nodes/block, 4 waves.
// ---------------------------------------------------------------------------
__global__ __launch_bounds__(256) void egnn_node_mfma(
    const float* __restrict__ h, const short* __restrict__ hb,
    const short* __restrict__ aggb, const float* __restrict__ pos,
    const float* __restrict__ dpos, const short* __restrict__ WnT,
    const float* __restrict__ bn, const float* __restrict__ lng,
    const float* __restrict__ lnb,
    float* __restrict__ h_out, float* __restrict__ pos_out, int N)
{
    __shared__ short As[64][136];   // cols 0..64 = h (bf16), 64..128 = agg
    const int tid = threadIdx.x;
    const int n0  = blockIdx.x * 64;

    if (tid < 64) {
        const int n = n0 + tid;
        if (n < N) {
            #pragma unroll
            for (int c = 0; c < 3; ++c)
                pos_out[(size_t)3 * n + c] = pos[(size_t)3 * n + c] + dpos[(size_t)3 * n + c];
        }
    }

    {
        const int row = tid >> 2, part = tid & 3;
        const int n = n0 + row;
        if (n < N) {
            const short* sp = (part < 2) ? (hb + (size_t)n * 64 + (part & 1) * 32)
                                         : (aggb + (size_t)n * 64 + (part & 1) * 32);
            #pragma unroll
            for (int q = 0; q < 4; ++q)
                *reinterpret_cast<short8*>(&As[row][part * 32 + q * 8]) =
                    *reinterpret_cast<const short8*>(sp + q * 8);
        }
    }
    __syncthreads();

    const int lane = tid & 63;
    const int wave = tid >> 6;
    const int r16  = lane & 15;
    const int kg   = lane >> 4;
    const int mrow = wave * 16 + r16;

    f32x4 acc[4];
    #pragma unroll
    for (int nt = 0; nt < 4; ++nt) {
        const float b = bn[r16 + nt * 16];
        acc[nt] = {b, b, b, b};
    }
    #pragma unroll
    for (int kt = 0; kt < 4; ++kt) {
        short8 a = *reinterpret_cast<const short8*>(&As[mrow][kt * 32 + kg * 8]);
        #pragma unroll
        for (int nt = 0; nt < 4; ++nt) {
            short8 b = *reinterpret_cast<const short8*>(
                &WnT[(r16 + nt * 16) * 128 + kt * 32 + kg * 8]);
            acc[nt] = __builtin_amdgcn_mfma_f32_16x16x32_bf16(a, b, acc[nt], 0, 0, 0);
        }
    }

    float xv[4][4];
    #pragma unroll
    for (int rg = 0; rg < 4; ++rg) {
        const int n = n0 + wave * 16 + kg * 4 + rg;
        const bool ok = n < N;
        #pragma unroll
        for (int nt = 0; nt < 4; ++nt)
            xv[nt][rg] = (ok ? h[(size_t)n * 64 + r16 + nt * 16] : 0.0f)
                         + fmaxf(acc[nt][rg], 0.0f);
    }

    float g[4], bb[4];
    #pragma unroll
    for (int nt = 0; nt < 4; ++nt) { g[nt] = lng[r16 + nt * 16]; bb[nt] = lnb[r16 + nt * 16]; }

    #pragma unroll
    for (int rg = 0; rg < 4; ++rg) {
        float s = xv[0][rg] + xv[1][rg] + xv[2][rg] + xv[3][rg];
        #pragma unroll
        for (int off = 1; off < 16; off <<= 1) s += __shfl_xor(s, off);
        const float mu = s * 0.015625f;
        float q = 0.0f;
        #pragma unroll
        for (int nt = 0; nt < 4; ++nt) { const float d = xv[nt][rg] - mu; q += d * d; }
        #pragma unroll
        for (int off = 1; off < 16; off <<= 1) q += __shfl_xor(q, off);
        const float inv = rsqrtf(q * 0.015625f + 1e-5f);
        const int n = n0 + wave * 16 + kg * 4 + rg;
        if (n < N) {
            #pragma unroll
            for (int nt = 0; nt < 4; ++nt)
                h_out[(size_t)n * 64 + r16 + nt * 16] =
                    (xv[nt][rg] - mu) * inv * g[nt] + bb[nt];
        }
    }
}

extern "C" void kernel_launch(void* const* d_in, const int* in_sizes, int n_in,
                              void* d_out, int out_size, void* d_ws, size_t ws_size,
                              hipStream_t stream)
{
    const float* h   = (const float*)d_in[0];
    const float* pos = (const float*)d_in[1];
    const int*   ei  = (const int*)d_in[2];
    const float* ea  = (const float*)d_in[3];
    const float* We1 = (const float*)d_in[4];
    const float* be1 = (const float*)d_in[5];
    const float* We2 = (const float*)d_in[6];
    const float* be2 = (const float*)d_in[7];
    const float* Wc1 = (const float*)d_in[8];
    const float* bc1 = (const float*)d_in[9];
    const float* Wc2 = (const float*)d_in[10];
    const float* bc2 = (const float*)d_in[11];
    const float* Wn  = (const float*)d_in[12];
    const float* bn  = (const float*)d_in[13];
    const float* lng = (const float*)d_in[14];
    const float* lnb = (const float*)d_in[15];

    const int N = in_sizes[0] / 64;
    const int E = in_sizes[2] / 2;
    const int NB = (N + 1023) / 1024;

    // workspace layout (16B-aligned short arrays first)
    short* aggb = (short*)d_ws;                         // [N,64] bf16
    short* hbuf = aggb + (size_t)N * 64;                // [N,64] bf16
    short* eaS  = hbuf + (size_t)N * 64;                // [E,16] bf16 (sorted)
    short* W1T  = eaS + (size_t)E * 16;                 // [64,160]
    short* W2T  = W1T + 64 * 160;                       // [64,64]
    short* Wc1T = W2T + 64 * 64;                        // [64,64]
    short* WnT  = Wc1T + 64 * 64;                       // [64,128]
    float* dpos = (float*)(WnT + 64 * 128);             // [N,3]  f32
    int* cnt    = (int*)(dpos + (size_t)3 * N);         // [N]
    int* cursor = cnt + N;                              // [N]
    int* startp = cursor + N;                           // [N+1]
    int* bsum   = startp + N + 1;                       // [NB<=1024]
    int* boff   = bsum + 1024;                          // [NB]
    int* srcS   = boff + 1024;                          // [E] (sorted)
    int* dstS   = srcS + E;                             // [E] (sorted)

    (void)hipMemsetAsync(aggb, 0, (size_t)N * 128, stream);     // aggb
    (void)hipMemsetAsync(dpos, 0, (size_t)N * 20, stream);      // dpos+cnt+cursor
    convert_weights<<<40, 256, 0, stream>>>(We1, We2, Wc1, Wn, W1T, W2T, Wc1T, WnT);
    convert_h<<<(N * 64 / 8 + 255) / 256, 256, 0, stream>>>(h, hbuf, N * 64 / 8);
    count_kernel<<<(E + 255) / 256, 256, 0, stream>>>(ei, cnt, E);
    scan_partial<<<NB, 1024, 0, stream>>>(cnt, bsum, N);
    scan_bsum<<<1, 1024, 0, stream>>>(bsum, boff, NB);
    scan_final<<<NB, 1024, 0, stream>>>(cnt, boff, startp, N, E);
    fill_gather<<<(E + 255) / 256, 256, 0, stream>>>(
        ei, ea, startp, cursor, srcS, dstS, eaS, E);

    float* h_out   = (float*)d_out;
    float* pos_out = h_out + (size_t)N * 64;

    // 2 tiles/wave, 4 waves/block -> 128 edges per block
    egnn_edge_sorted<<<(E + 127) / 128, 256, 0, stream>>>(
        hbuf, pos, srcS, dstS, eaS, W1T, W2T, Wc1T,
        be1, be2, bc1, bc2, Wc2, aggb, dpos, E);
    egnn_node_mfma<<<(N + 63) / 64, 256, 0, stream>>>(
        h, hbuf, aggb, pos, dpos, WnT, bn, lng, lnb, h_out, pos_out, N);
}